// Round 11
// baseline (93.169 us; speedup 1.0000x reference)
//
#include <hip/hip_runtime.h>
#include <math.h>

#define BB 4
#define NN 2048
#define MM 128
#define DD 64
#define NEG_SLOPE 0.2f

#define MT 16                 // m per block
#define NMT (MM / MT)         // 8 m-tiles
#define NSPL 16               // n splits
#define NR (NN / NSPL)        // 128 n per block
#define PSTR 132              // p_lds row stride
#define QSTR 68               // q_tot row stride (bank-spread)

// ---------------------------------------------------------------------------
// mega: per (ns, mt, b) block.
//  0 : stage fs chunk; v_l = W_src^T.attn_l ; u_r = W_dst^T.attn_r ; c_e
//  0b: el[n] = fs[n,:].v_l (rotated k for bank spread); er[m] = fd[m,:].u_r
//  1 : scores p = exp(masked leaky)   (R10 pattern)
//  2 : q[m,k] partial = sum_n p*fs    (R10 agg pattern, fs-space)
//  3 : write pacc/pdn; release fence; last block per (b,mt) reduces over ns,
//      applies W_src transform, sigmoid, writes out.
// ---------------------------------------------------------------------------
__global__ __launch_bounds__(256, 3) void mega_kernel(
        const float* __restrict__ fs, const float* __restrict__ W_src,
        const float* __restrict__ attn_l,
        const float* __restrict__ fd, const float* __restrict__ W_dst,
        const float* __restrict__ attn_r,
        const float* __restrict__ W_edge, const float* __restrict__ attn_e,
        const float* __restrict__ fe, const int* __restrict__ adj,
        float* __restrict__ pacc, float* __restrict__ pdn,
        unsigned* __restrict__ cnt, float* __restrict__ out) {
    int ns = blockIdx.x, mt = blockIdx.y, b = blockIdx.z;
    int n0 = ns * NR, m0 = mt * MT;
    int t = threadIdx.x, lane = t & 63;

    __shared__ __align__(16) float fsh[NR * DD];     // 32 KB: fs / partials / W_T
    __shared__ __align__(16) float p_lds[MT * PSTR]; // 8.25 KB: p / q_tot
    __shared__ float el_lds[NR];
    __shared__ float er_lds[MT];
    __shared__ float vl[DD], ur[DD];
    __shared__ float dred[16][17], fred[16][17];
    __shared__ float ce_s;
    __shared__ unsigned lastflag;

    // ---- phase 0 ----
    const float4* fs4 = (const float4*)(fs + ((size_t)(b * NN + n0)) * DD);
#pragma unroll 4
    for (int k = 0; k < 8; ++k)
        ((float4*)fsh)[t + k * 256] = fs4[t + k * 256];

    if (t < 64) {                         // v_l
        float a = 0.f;
#pragma unroll 8
        for (int d2 = 0; d2 < DD; ++d2) a += attn_l[d2] * W_src[d2 * DD + t];
        vl[t] = a;
    } else if (t < 128) {                 // u_r
        float a = 0.f;
#pragma unroll 8
        for (int d2 = 0; d2 < DD; ++d2) a += attn_r[d2] * W_dst[d2 * DD + lane];
        ur[lane] = a;
    } else if (t < 192) {                 // c_e
        float v = W_edge[lane] * attn_e[lane];
#pragma unroll
        for (int off = 32; off > 0; off >>= 1) v += __shfl_xor(v, off, 64);
        if (lane == 0) ce_s = v;
    }
    __syncthreads();

    // ---- phase 0b: el + er ----
    if (t < NR) {
        int n = t;
        float a = 0.f;
#pragma unroll 8
        for (int j = 0; j < DD; ++j) {
            int k = (n + j) & 63;         // rotation: 2-way max
            a += fsh[n * DD + k] * vl[k];
        }
        el_lds[n] = a;
    } else if (t < 128 + MT) {
        int m = t - 128;
        float a = 0.f;
        const float* fdp = fd + (size_t)(b * MM + m0 + m) * DD;
#pragma unroll 8
        for (int k = 0; k < DD; ++k) a += fdp[k] * ur[k];
        er_lds[m] = a;
    }
    __syncthreads();

    // ---- phase 1: scores (m = t&15, h = t>>4), n = h + 16j ----
    {
        int m = t & 15, h = t >> 4;
        float ce = ce_s;
        float er_m = er_lds[m];
        const float* fe_p = fe + ((size_t)(b * NN + n0)) * MM + m0 + m;
        const int* adj_p = adj + ((size_t)(b * NN + n0)) * MM + m0 + m;
        float dsum = 0.f, fsum = 0.f;
#pragma unroll 4
        for (int j = 0; j < 8; ++j) {
            int n = h + j * 16;
            float f = fe_p[(size_t)n * MM];
            int a = adj_p[(size_t)n * MM];
            float s = el_lds[n] + ce * f + er_m;
            s = s > 0.f ? s : NEG_SLOPE * s;
            float p = (a == 1) ? __expf(s) : 0.f;
            p_lds[m * PSTR + n] = p;
            dsum += p;
            fsum += f * p;
        }
        dred[h][m] = dsum;
        fred[h][m] = fsum;
    }
    __syncthreads();

    // ---- phase 2: q-agg (nq = t>>6, mh = (t>>5)&1, kq = t&31) ----
    float acc[8][2];
    {
        int nq = t >> 6, mh = (t >> 5) & 1, kq = t & 31;
#pragma unroll
        for (int i = 0; i < 8; ++i) { acc[i][0] = 0.f; acc[i][1] = 0.f; }
        int rbase = mh * 8 * PSTR;
#pragma unroll 2
        for (int n4 = 0; n4 < 8; ++n4) {
            int nb = nq * 32 + n4 * 4;
            float2 h0 = *(const float2*)&fsh[(nb + 0) * DD + kq * 2];
            float2 h1 = *(const float2*)&fsh[(nb + 1) * DD + kq * 2];
            float2 h2 = *(const float2*)&fsh[(nb + 2) * DD + kq * 2];
            float2 h3 = *(const float2*)&fsh[(nb + 3) * DD + kq * 2];
#pragma unroll
            for (int mj = 0; mj < 8; ++mj) {
                float4 p4 = *(const float4*)&p_lds[rbase + mj * PSTR + nb];
                acc[mj][0] += p4.x * h0.x + p4.y * h1.x + p4.z * h2.x + p4.w * h3.x;
                acc[mj][1] += p4.x * h0.y + p4.y * h1.y + p4.z * h2.y + p4.w * h3.y;
            }
        }
    }
    __syncthreads();                      // agg reads of fsh done

    // ---- partials into fsh[nq][m][k] ----
    {
        int nq = t >> 6, mh = (t >> 5) & 1, kq = t & 31;
        float* part = fsh + nq * (MT * DD);
#pragma unroll
        for (int mj = 0; mj < 8; ++mj)
            *(float2*)&part[(mh * 8 + mj) * DD + kq * 2] =
                make_float2(acc[mj][0], acc[mj][1]);
    }
    __syncthreads();

    // ---- sum 4 partials -> pacc (q); pdn ----
    size_t pbase = (size_t)((b * NMT + mt) * NSPL + ns) * MT;
    {
        int m = t >> 4, ks = t & 15;
        float4 s0 = *(const float4*)&fsh[0 * MT * DD + m * DD + ks * 4];
        float4 s1 = *(const float4*)&fsh[1 * MT * DD + m * DD + ks * 4];
        float4 s2 = *(const float4*)&fsh[2 * MT * DD + m * DD + ks * 4];
        float4 s3 = *(const float4*)&fsh[3 * MT * DD + m * DD + ks * 4];
        float4 o;
        o.x = s0.x + s1.x + s2.x + s3.x;
        o.y = s0.y + s1.y + s2.y + s3.y;
        o.z = s0.z + s1.z + s2.z + s3.z;
        o.w = s0.w + s1.w + s2.w + s3.w;
        *(float4*)&pacc[(pbase + m) * DD + ks * 4] = o;
    }
    if (t < MT) {
        float ds2 = 0.f, fs2 = 0.f;
#pragma unroll
        for (int k = 0; k < 16; ++k) { ds2 += dred[k][t]; fs2 += fred[k][t]; }
        size_t q = (pbase + t) * 2;
        pdn[q] = ds2;
        pdn[q + 1] = fs2;
    }

    // ---- release fence + elect last block of this (b,mt) ----
    __threadfence();
    __syncthreads();
    if (t == 0) {
        unsigned old = atomicAdd(&cnt[b * NMT + mt], 1u);
        lastflag = (old == NSPL - 1) ? 1u : 0u;
    }
    __syncthreads();
    if (lastflag == 0u) return;
    __threadfence();                      // acquire: see siblings' pacc/pdn

    // ---- last block: reduce over ns + W_src transform + sigmoid ----
    float* WT = fsh;                      // [k][d] transposed W_src (16 KB)
    float* q_tot = p_lds;                 // [MT][QSTR]
    float* dn_tot = el_lds;               // 16
    float* sf_tot = el_lds + 32;          // 16
#pragma unroll
    for (int i = 0; i < 16; ++i) {
        int idx = t + i * 256;            // 0..4095
        int k = idx >> 6, d = idx & 63;
        WT[idx] = W_src[d * DD + k];
    }
    {
        int m = t >> 4, kq = t & 15;
        size_t base = (size_t)((b * NMT + mt) * NSPL) * MT;
        float4 s = make_float4(0.f, 0.f, 0.f, 0.f);
#pragma unroll
        for (int nsj = 0; nsj < NSPL; ++nsj) {
            float4 v = *(const float4*)&pacc[(base + nsj * MT + m) * DD + kq * 4];
            s.x += v.x; s.y += v.y; s.z += v.z; s.w += v.w;
        }
        *(float4*)&q_tot[m * QSTR + kq * 4] = s;
    }
    if (t < MT) {
        size_t base = (size_t)((b * NMT + mt) * NSPL) * MT;
        float ds2 = 0.f, fs2 = 0.f;
#pragma unroll
        for (int nsj = 0; nsj < NSPL; ++nsj) {
            size_t q = (base + nsj * MT + t) * 2;
            ds2 += pdn[q];
            fs2 += pdn[q + 1];
        }
        dn_tot[t] = ds2;
        sf_tot[t] = fs2;
    }
    __syncthreads();
    {
        int m = t >> 4, dq = t & 15;
        float4 r = make_float4(0.f, 0.f, 0.f, 0.f);
#pragma unroll 8
        for (int k = 0; k < DD; ++k) {
            float qv = q_tot[m * QSTR + k];
            float4 wv = *(const float4*)&WT[k * DD + dq * 4];
            r.x += wv.x * qv; r.y += wv.y * qv;
            r.z += wv.z * qv; r.w += wv.w * qv;
        }
        float inv = 1.f / dn_tot[m];
        float sfe = sf_tot[m];
        float4 we = *(const float4*)&W_edge[dq * 4];
        float4 o;
        o.x = 1.f / (1.f + __expf(-(we.x * sfe + r.x) * inv));
        o.y = 1.f / (1.f + __expf(-(we.y * sfe + r.y) * inv));
        o.z = 1.f / (1.f + __expf(-(we.z * sfe + r.z) * inv));
        o.w = 1.f / (1.f + __expf(-(we.w * sfe + r.w) * inv));
        *(float4*)&out[((size_t)(b * MM + m0 + m)) * DD + dq * 4] = o;
    }
}

extern "C" void kernel_launch(void* const* d_in, const int* in_sizes, int n_in,
                              void* d_out, int out_size, void* d_ws, size_t ws_size,
                              hipStream_t stream) {
    const float* feat_src  = (const float*)d_in[0];
    const float* feat_dst  = (const float*)d_in[1];
    const float* feat_edge = (const float*)d_in[2];
    const int*   adj       = (const int*)d_in[3];
    const float* W_src     = (const float*)d_in[4];
    const float* W_dst     = (const float*)d_in[5];
    const float* W_edge    = (const float*)d_in[6];
    const float* attn_l    = (const float*)d_in[7];
    const float* attn_r    = (const float*)d_in[8];
    const float* attn_e    = (const float*)d_in[9];
    float* out = (float*)d_out;

    float* ws   = (float*)d_ws;
    float* pacc = ws;                                        // 524288
    float* pdn  = pacc + (size_t)BB * NMT * NSPL * MT * DD;  // 16384
    unsigned* cnt = (unsigned*)(pdn + (size_t)BB * NMT * NSPL * MT * 2); // 32

    hipMemsetAsync(cnt, 0, (size_t)BB * NMT * sizeof(unsigned), stream);
    mega_kernel<<<dim3(NSPL, NMT, BB), 256, 0, stream>>>(
        feat_src, W_src, attn_l, feat_dst, W_dst, attn_r,
        W_edge, attn_e, feat_edge, adj, pacc, pdn, cnt, out);
}

// Round 12
// 19.801 us; speedup vs baseline: 4.7054x; 4.7054x over previous
//
#include <hip/hip_runtime.h>
#include <math.h>

#define BB 4
#define NN 2048
#define MM 128
#define DD 64
#define NEG_SLOPE 0.2f

#define MT 16                 // m per block
#define NMT (MM / MT)         // 8 m-tiles
#define NSPL 16               // n splits
#define NR (NN / NSPL)        // 128 n per block
#define PSTR 132              // p_lds row stride
#define QSTR 68               // q_tot row stride (bank-spread)

// ---------------------------------------------------------------------------
// K1: per (ns, mt, b) block — proj-free (fs-space aggregation):
//  0 : stage fs chunk; v_l = W_src^T.attn_l ; u_r = W_dst^T.attn_r ; c_e
//  0b: el[n] = fs[n,:].v_l ; er[m] = fd[m,:].u_r
//  1 : scores p = exp(masked leaky)
//  2 : q[m,k] partial = sum_n p*fs  -> pacc ; denom/sfe -> pdn
// ---------------------------------------------------------------------------
__global__ __launch_bounds__(256, 3) void fused_kernel(
        const float* __restrict__ fs, const float* __restrict__ W_src,
        const float* __restrict__ attn_l,
        const float* __restrict__ fd, const float* __restrict__ W_dst,
        const float* __restrict__ attn_r,
        const float* __restrict__ W_edge, const float* __restrict__ attn_e,
        const float* __restrict__ fe, const int* __restrict__ adj,
        float* __restrict__ pacc, float* __restrict__ pdn) {
    int ns = blockIdx.x, mt = blockIdx.y, b = blockIdx.z;
    int n0 = ns * NR, m0 = mt * MT;
    int t = threadIdx.x, lane = t & 63;

    __shared__ __align__(16) float fsh[NR * DD];     // 32 KB: fs, then partials
    __shared__ __align__(16) float p_lds[MT * PSTR]; // 8.25 KB
    __shared__ float el_lds[NR];
    __shared__ float er_lds[MT];
    __shared__ float vl[DD], ur[DD];
    __shared__ float dred[16][17], fred[16][17];
    __shared__ float ce_s;

    // ---- phase 0 ----
    const float4* fs4 = (const float4*)(fs + ((size_t)(b * NN + n0)) * DD);
#pragma unroll 4
    for (int k = 0; k < 8; ++k)
        ((float4*)fsh)[t + k * 256] = fs4[t + k * 256];

    if (t < 64) {                         // v_l = W_src^T . attn_l
        float a = 0.f;
#pragma unroll 8
        for (int d2 = 0; d2 < DD; ++d2) a += attn_l[d2] * W_src[d2 * DD + t];
        vl[t] = a;
    } else if (t < 128) {                 // u_r = W_dst^T . attn_r
        float a = 0.f;
#pragma unroll 8
        for (int d2 = 0; d2 < DD; ++d2) a += attn_r[d2] * W_dst[d2 * DD + lane];
        ur[lane] = a;
    } else if (t < 192) {                 // c_e
        float v = W_edge[lane] * attn_e[lane];
#pragma unroll
        for (int off = 32; off > 0; off >>= 1) v += __shfl_xor(v, off, 64);
        if (lane == 0) ce_s = v;
    }
    __syncthreads();

    // ---- phase 0b: el + er ----
    if (t < NR) {
        int n = t;
        float a = 0.f;
#pragma unroll 8
        for (int j = 0; j < DD; ++j) {
            int k = (n + j) & 63;         // rotation: <=2-way banks
            a += fsh[n * DD + k] * vl[k];
        }
        el_lds[n] = a;
    } else if (t < 128 + MT) {
        int m = t - 128;
        float a = 0.f;
        const float* fdp = fd + (size_t)(b * MM + m0 + m) * DD;
#pragma unroll 8
        for (int k = 0; k < DD; ++k) a += fdp[k] * ur[k];
        er_lds[m] = a;
    }
    __syncthreads();

    // ---- phase 1: scores (m = t&15, h = t>>4), n = h + 16j ----
    {
        int m = t & 15, h = t >> 4;
        float ce = ce_s;
        float er_m = er_lds[m];
        const float* fe_p = fe + ((size_t)(b * NN + n0)) * MM + m0 + m;
        const int* adj_p = adj + ((size_t)(b * NN + n0)) * MM + m0 + m;
        float dsum = 0.f, fsum = 0.f;
#pragma unroll 4
        for (int j = 0; j < 8; ++j) {
            int n = h + j * 16;
            float f = fe_p[(size_t)n * MM];
            int a = adj_p[(size_t)n * MM];
            float s = el_lds[n] + ce * f + er_m;
            s = s > 0.f ? s : NEG_SLOPE * s;
            float p = (a == 1) ? __expf(s) : 0.f;
            p_lds[m * PSTR + n] = p;
            dsum += p;
            fsum += f * p;
        }
        dred[h][m] = dsum;
        fred[h][m] = fsum;
    }
    __syncthreads();

    // ---- phase 2: q-agg (nq = t>>6, mh = (t>>5)&1, kq = t&31) ----
    float acc[8][2];
    {
        int nq = t >> 6, mh = (t >> 5) & 1, kq = t & 31;
#pragma unroll
        for (int i = 0; i < 8; ++i) { acc[i][0] = 0.f; acc[i][1] = 0.f; }
        int rbase = mh * 8 * PSTR;
#pragma unroll 2
        for (int n4 = 0; n4 < 8; ++n4) {
            int nb = nq * 32 + n4 * 4;
            float2 h0 = *(const float2*)&fsh[(nb + 0) * DD + kq * 2];
            float2 h1 = *(const float2*)&fsh[(nb + 1) * DD + kq * 2];
            float2 h2 = *(const float2*)&fsh[(nb + 2) * DD + kq * 2];
            float2 h3 = *(const float2*)&fsh[(nb + 3) * DD + kq * 2];
#pragma unroll
            for (int mj = 0; mj < 8; ++mj) {
                float4 p4 = *(const float4*)&p_lds[rbase + mj * PSTR + nb];
                acc[mj][0] += p4.x * h0.x + p4.y * h1.x + p4.z * h2.x + p4.w * h3.x;
                acc[mj][1] += p4.x * h0.y + p4.y * h1.y + p4.z * h2.y + p4.w * h3.y;
            }
        }
    }
    __syncthreads();                      // agg reads of fsh done

    // ---- partials into fsh[nq][m][k] ----
    {
        int nq = t >> 6, mh = (t >> 5) & 1, kq = t & 31;
        float* part = fsh + nq * (MT * DD);
#pragma unroll
        for (int mj = 0; mj < 8; ++mj)
            *(float2*)&part[(mh * 8 + mj) * DD + kq * 2] =
                make_float2(acc[mj][0], acc[mj][1]);
    }
    __syncthreads();

    // ---- sum 4 partials -> pacc (q); pdn ----
    size_t pbase = (size_t)((b * NMT + mt) * NSPL + ns) * MT;
    {
        int m = t >> 4, ks = t & 15;
        float4 s0 = *(const float4*)&fsh[0 * MT * DD + m * DD + ks * 4];
        float4 s1 = *(const float4*)&fsh[1 * MT * DD + m * DD + ks * 4];
        float4 s2 = *(const float4*)&fsh[2 * MT * DD + m * DD + ks * 4];
        float4 s3 = *(const float4*)&fsh[3 * MT * DD + m * DD + ks * 4];
        float4 o;
        o.x = s0.x + s1.x + s2.x + s3.x;
        o.y = s0.y + s1.y + s2.y + s3.y;
        o.z = s0.z + s1.z + s2.z + s3.z;
        o.w = s0.w + s1.w + s2.w + s3.w;
        *(float4*)&pacc[(pbase + m) * DD + ks * 4] = o;
    }
    if (t < MT) {
        float ds2 = 0.f, fs2 = 0.f;
#pragma unroll
        for (int k = 0; k < 16; ++k) { ds2 += dred[k][t]; fs2 += fred[k][t]; }
        size_t q = (pbase + t) * 2;
        pdn[q] = ds2;
        pdn[q + 1] = fs2;
    }
}

// ---------------------------------------------------------------------------
// K2: per (mt, b) block: q_tot = sum_ns pacc; out = sigmoid((W_src.q_tot +
//     W_edge*sfe)/denom)  — 32 blocks, tiny.
// ---------------------------------------------------------------------------
__global__ __launch_bounds__(256) void finish_kernel(
        const float* __restrict__ pacc, const float* __restrict__ pdn,
        const float* __restrict__ W_src, const float* __restrict__ W_edge,
        float* __restrict__ out) {
    int mt = blockIdx.x, b = blockIdx.y;
    int m0 = mt * MT;
    int t = threadIdx.x;

    __shared__ __align__(16) float WT[DD * DD];       // [k][d] = W_src[d][k]
    __shared__ __align__(16) float q_tot[MT * QSTR];
    __shared__ float dn_tot[MT], sf_tot[MT];

#pragma unroll
    for (int i = 0; i < 16; ++i) {
        int idx = t + i * 256;            // 0..4095
        int k = idx >> 6, d = idx & 63;
        WT[idx] = W_src[d * DD + k];      // LDS writes consecutive: no conflict
    }
    {
        int m = t >> 4, kq = t & 15;
        size_t base = (size_t)((b * NMT + mt) * NSPL) * MT;
        float4 s = make_float4(0.f, 0.f, 0.f, 0.f);
#pragma unroll
        for (int nsj = 0; nsj < NSPL; ++nsj) {
            float4 v = *(const float4*)&pacc[(base + nsj * MT + m) * DD + kq * 4];
            s.x += v.x; s.y += v.y; s.z += v.z; s.w += v.w;
        }
        *(float4*)&q_tot[m * QSTR + kq * 4] = s;
    }
    if (t < MT) {
        size_t base = (size_t)((b * NMT + mt) * NSPL) * MT;
        float ds2 = 0.f, fs2 = 0.f;
#pragma unroll
        for (int nsj = 0; nsj < NSPL; ++nsj) {
            size_t q = (base + nsj * MT + t) * 2;
            ds2 += pdn[q];
            fs2 += pdn[q + 1];
        }
        dn_tot[t] = ds2;
        sf_tot[t] = fs2;
    }
    __syncthreads();
    {
        int m = t >> 4, dq = t & 15;
        float4 r = make_float4(0.f, 0.f, 0.f, 0.f);
#pragma unroll 8
        for (int k = 0; k < DD; ++k) {
            float qv = q_tot[m * QSTR + k];               // broadcast per 16-group
            float4 wv = *(const float4*)&WT[k * DD + dq * 4];
            r.x += wv.x * qv; r.y += wv.y * qv;
            r.z += wv.z * qv; r.w += wv.w * qv;
        }
        float inv = 1.f / dn_tot[m];
        float sfe = sf_tot[m];
        float4 we = *(const float4*)&W_edge[dq * 4];
        float4 o;
        o.x = 1.f / (1.f + __expf(-(we.x * sfe + r.x) * inv));
        o.y = 1.f / (1.f + __expf(-(we.y * sfe + r.y) * inv));
        o.z = 1.f / (1.f + __expf(-(we.z * sfe + r.z) * inv));
        o.w = 1.f / (1.f + __expf(-(we.w * sfe + r.w) * inv));
        *(float4*)&out[((size_t)(b * MM + m0 + m)) * DD + dq * 4] = o;
    }
}

extern "C" void kernel_launch(void* const* d_in, const int* in_sizes, int n_in,
                              void* d_out, int out_size, void* d_ws, size_t ws_size,
                              hipStream_t stream) {
    const float* feat_src  = (const float*)d_in[0];
    const float* feat_dst  = (const float*)d_in[1];
    const float* feat_edge = (const float*)d_in[2];
    const int*   adj       = (const int*)d_in[3];
    const float* W_src     = (const float*)d_in[4];
    const float* W_dst     = (const float*)d_in[5];
    const float* W_edge    = (const float*)d_in[6];
    const float* attn_l    = (const float*)d_in[7];
    const float* attn_r    = (const float*)d_in[8];
    const float* attn_e    = (const float*)d_in[9];
    float* out = (float*)d_out;

    float* ws   = (float*)d_ws;
    float* pacc = ws;                                        // 524288
    float* pdn  = pacc + (size_t)BB * NMT * NSPL * MT * DD;  // 16384

    fused_kernel<<<dim3(NSPL, NMT, BB), 256, 0, stream>>>(
        feat_src, W_src, attn_l, feat_dst, W_dst, attn_r,
        W_edge, attn_e, feat_edge, adj, pacc, pdn);
    finish_kernel<<<dim3(NMT, BB), 256, 0, stream>>>(
        pacc, pdn, W_src, W_edge, out);
}